// Round 9
// baseline (131.978 us; speedup 1.0000x reference)
//
#include <hip/hip_runtime.h>

#define BS 4
#define NQ 16384
#define GTOK 65536   // BS * NQ

typedef unsigned short u16;
typedef unsigned int u32;
typedef __attribute__((ext_vector_type(8))) short bf16x8;   // 8 bf16 (4 VGPRs)
typedef __attribute__((ext_vector_type(4))) short bf16x4;   // 4 bf16
typedef __attribute__((ext_vector_type(4))) float f32x4;
typedef __attribute__((ext_vector_type(2))) float f32x2;
typedef __attribute__((ext_vector_type(4))) unsigned int u32x4;

__device__ __forceinline__ float bf2f(u16 v) { return __uint_as_float(((u32)v) << 16); }
__device__ __forceinline__ u16 f2bf(float f) {
    u32 u = __float_as_uint(f);
    u32 r = (u + 0x7fffu + ((u >> 16) & 1u)) >> 16;   // RNE, finite inputs only
    return (u16)r;
}
// NOTE (R5 post-mortem): inline-asm v_cvt_pk_bf16_f32 measured -42% on the
// fused kernel (reproduces learn_hip m240's -37%). Keep the bit-twiddle.
__device__ __forceinline__ u32 pk2bf(float lo, float hi) {
    return (u32)f2bf(lo) | ((u32)f2bf(hi) << 16);
}
// Build an MFMA A-frag (8 bf16) from 8 contiguous f32.
__device__ __forceinline__ bf16x8 make_afrag(const float* qrow) {
    f32x4 q0 = *(const f32x4*)(qrow);
    f32x4 q1 = *(const f32x4*)(qrow + 4);
    union { bf16x8 v; u32 u[4]; } a;
    a.u[0] = pk2bf(q0.x, q0.y); a.u[1] = pk2bf(q0.z, q0.w);
    a.u[2] = pk2bf(q1.x, q1.y); a.u[3] = pk2bf(q1.z, q1.w);
    return a.v;
}

// ---------------------------------------------------------------------------
// Setup: swizzle weights into MFMA B-frag order (bf16).
// B-frag: b[j] = B[k = kb*32 + quad*8 + j][n = nt*16 + lane16], flat index
// (((nt*4+kb)*4+quad)*16 + lane16)*8 + j.
// Proj B = [W_val | W_off | W_attn] (128 x 224): nt 0..13. W_out: nt 0..7.
// ---------------------------------------------------------------------------
__global__ __launch_bounds__(256)
void setup_kernel(const float* __restrict__ W_val, const float* __restrict__ W_off,
                  const float* __restrict__ W_attn, const float* __restrict__ W_out,
                  u16* __restrict__ Wswz, u16* __restrict__ Wout_swz)
{
    const int i = blockIdx.x * 256 + threadIdx.x;
    if (i < 28672) {                       // proj swizzle (14 nt)
        const int j = i & 7, lane = (i >> 3) & 15, quad = (i >> 7) & 3;
        const int kb = (i >> 9) & 3, nt = i >> 11;
        const int k = kb * 32 + quad * 8 + j;
        const int n = nt * 16 + lane;
        float v;
        if (n < 128)      v = W_val[k * 128 + n];
        else if (n < 192) v = W_off[k * 64 + (n - 128)];
        else              v = W_attn[k * 32 + (n - 192)];
        Wswz[i] = f2bf(v);
    } else if (i < 45056) {                // W_out swizzle (8 nt)
        const int i2 = i - 28672;
        const int j = i2 & 7, lane = (i2 >> 3) & 15, quad = (i2 >> 7) & 3;
        const int kb = (i2 >> 9) & 3, nt = i2 >> 11;
        const int k = kb * 32 + quad * 8 + j;
        const int n = nt * 16 + lane;
        Wout_swz[i2] = f2bf(W_out[k * 128 + n]);
    }
}

// ---------------------------------------------------------------------------
// Pre-pass (R9: val ONLY): value projection for ALL 65536 tokens.
// off/attn moved back into the fused kernel (own-token, no halo duplication —
// routing it through HBM was a pure 24 MB round-trip with zero dedup benefit).
// ---------------------------------------------------------------------------
__global__ __launch_bounds__(256)
void prepass_kernel(const float* __restrict__ query,
                    const float* __restrict__ b_val,
                    const u16* __restrict__ Wswz,
                    u16* __restrict__ val)
{
    __shared__ __align__(16) u16 stage[64 * 136];   // 17408 B
    const int tid = threadIdx.x;
    const int w = tid >> 6, l = tid & 63;
    const int lane16 = l & 15, quad = l >> 4;
    const int gtok0 = blockIdx.x * 64;
    const bf16x8* Wf = (const bf16x8*)Wswz;

    // A-frags for this wave's 16 tokens
    const int tl = w * 16 + lane16;
    const float* qrow = query + (size_t)(gtok0 + tl) * 128 + quad * 8;
    bf16x8 afrag[4];
    #pragma unroll
    for (int kb = 0; kb < 4; ++kb)
        afrag[kb] = make_afrag(qrow + kb * 32);

    // val: nt 0..7 -> stage rows stride 136 (quad-group writes are 2-way = free)
    #pragma unroll
    for (int nt = 0; nt < 8; ++nt) {
        f32x4 acc = {0.f, 0.f, 0.f, 0.f};
        const bf16x8* bp = Wf + ((size_t)(nt * 4) * 4 + quad) * 16 + lane16;
        #pragma unroll
        for (int kb = 0; kb < 4; ++kb)
            acc = __builtin_amdgcn_mfma_f32_16x16x32_bf16(afrag[kb], bp[kb * 64], acc, 0, 0, 0);
        const float bias = b_val[nt * 16 + lane16];
        #pragma unroll
        for (int r = 0; r < 4; ++r)
            stage[(w * 16 + quad * 4 + r) * 136 + nt * 16 + lane16] = f2bf(acc[r] + bias);
    }
    __syncthreads();
    // readback: 64 rows x 16 chunks of 16 B, coalesced full-line stores
    #pragma unroll
    for (int i = 0; i < 4; ++i) {
        const int chunk = i * 256 + tid;          // 0..1023
        const int t = chunk >> 4, c16 = chunk & 15;
        u32x4 v = *(const u32x4*)&stage[t * 136 + c16 * 8];
        *(u32x4*)&val[(size_t)(gtok0 + t) * 128 + c16 * 8] = v;
    }
}

// ---------------------------------------------------------------------------
// Fused kernel: block = 8x8 token square + 11x11 val halo (from prepass).
// Halo recentred: origin (X-2+(X>>6), Y-2+(Y>>6)) tracks the +1 px drift of
// cx = qx*128/127; >=1 px (4.4 sigma) margin; out-of-grid corners masked.
// 3 blocks/CU (R8: occupancy null in this regime; keep smaller LDS).
//   L2: halo val bf16 -> vhalo (stride 136, head swizzle), coalesced
//   1a: own-token off/attn proj (MFMA vs Wswz nt 8..13) -> scratch (R6 verbatim)
//   2a: softmax -> regs; 2b: bilinear gather (pk_fma) -> s tile;
//   2c: out MFMA + bias -> f32 stage in vhalo, coalesced full-line epilogue
//       with the 2*query residual.
// C/D layout: col = lane&15, row = quad*4 + reg  [measured m89].
// ---------------------------------------------------------------------------
__global__ __launch_bounds__(256, 3)
void fused_kernel(const float* __restrict__ query,
                  const float* __restrict__ b_off, const float* __restrict__ b_attn,
                  const float* __restrict__ b_out,
                  const u16* __restrict__ Wswz, const u16* __restrict__ Wout_swz,
                  const u16* __restrict__ val,
                  float* __restrict__ out)
{
    __shared__ __align__(16) u16 vhalo[121 * 136];   // 32912 B (also 2c f32 stage)
    __shared__ __align__(16) u16 scratch[64 * 136];  // 17408 B (off/attn then s tile)

    const int tid = threadIdx.x;
    const int bid = blockIdx.x;
    const int b_  = bid >> 8;          // batch
    const int sq  = bid & 255;
    const int Y   = (sq >> 4) * 8;
    const int X   = (sq & 15) * 8;
    const int HOX = X - 2 + (X >> 6);  // halo origin (recentred)
    const int HOY = Y - 2 + (Y >> 6);

    const int w = tid >> 6, l = tid & 63;
    const int lane16 = l & 15, quad = l >> 4;
    const size_t batch_base = (size_t)b_ * NQ;

    const bf16x8* Wf  = (const bf16x8*)Wswz;
    const bf16x8* WfO = (const bf16x8*)Wout_swz;

    // ---------------- L2: halo val -> vhalo (swizzled), loads issued first -----
    #pragma unroll
    for (int i = 0; i < 8; ++i) {
        const int chunk = i * 256 + tid;          // 0..2047, use 0..1935
        if (chunk < 1936) {
            const int hp = chunk >> 4, c16 = chunk & 15;
            const int hy = hp / 11, hx = hp - hy * 11;
            const int gy = min(max(HOY + hy, 0), 127);
            const int gx = min(max(HOX + hx, 0), 127);
            const size_t gt = batch_base + (size_t)gy * 128 + gx;
            u32x4 v = *(const u32x4*)&val[gt * 128 + c16 * 8];
            const int col = ((((c16 >> 1) + hp) & 7) << 4) + ((c16 & 1) << 3);
            *(u32x4*)&vhalo[hp * 136 + col] = v;
        }
    }
    // ---------------- 1a: own-token off/attn proj -> scratch (R6 verbatim) -----
    {
        const int tl = w * 16 + lane16;                 // own token 0..63
        const int ty = tl >> 3, tx = tl & 7;
        const size_t grow = batch_base + (size_t)(Y + ty) * 128 + (X + tx);
        const float* qrow = query + grow * 128 + quad * 8;
        bf16x8 afrag[4];
        #pragma unroll
        for (int kb = 0; kb < 4; ++kb)
            afrag[kb] = make_afrag(qrow + kb * 32);
        #pragma unroll
        for (int nt = 8; nt < 14; ++nt) {
            f32x4 acc = {0.f, 0.f, 0.f, 0.f};
            const bf16x8* bp = Wf + ((size_t)(nt * 4) * 4 + quad) * 16 + lane16;
            #pragma unroll
            for (int kb = 0; kb < 4; ++kb)
                acc = __builtin_amdgcn_mfma_f32_16x16x32_bf16(afrag[kb], bp[kb * 64], acc, 0, 0, 0);
            if (nt < 12) {                 // off cols c = (nt-8)*16 + lane16
                const int c = (nt - 8) * 16 + lane16;
                const float bias = b_off[c];
                #pragma unroll
                for (int r = 0; r < 4; ++r)
                    scratch[(w * 16 + quad * 4 + r) * 96 + c] = f2bf(acc[r] + bias);
            } else {                       // attn cols c = (nt-12)*16 + lane16
                const int c = (nt - 12) * 16 + lane16;
                const float bias = b_attn[c];
                #pragma unroll
                for (int r = 0; r < 4; ++r)
                    scratch[(w * 16 + quad * 4 + r) * 96 + 64 + c] = f2bf(acc[r] + bias);
            }
        }
    }
    __syncthreads();

    // ---------------- 2a: off/attn -> regs (softmax over 4 pts) ----------------
    float aw[2][4], ox[2][4], oy[2][4];
    #pragma unroll
    for (int it = 0; it < 2; ++it) {
        const int item = it * 256 + tid;
        const int t = item >> 3, h = item & 7;
        bf16x8 ofr = *(const bf16x8*)&scratch[t * 96 + h * 8];
        bf16x4 atr = *(const bf16x4*)&scratch[t * 96 + 64 + h * 4];
        #pragma unroll
        for (int p = 0; p < 4; ++p) {
            ox[it][p] = bf2f((u16)ofr[2 * p]);
            oy[it][p] = bf2f((u16)ofr[2 * p + 1]);
        }
        const float l0 = bf2f((u16)atr[0]), l1 = bf2f((u16)atr[1]);
        const float l2 = bf2f((u16)atr[2]), l3 = bf2f((u16)atr[3]);
        const float m = fmaxf(fmaxf(l0, l1), fmaxf(l2, l3));
        const float e0 = __expf(l0 - m), e1 = __expf(l1 - m);
        const float e2 = __expf(l2 - m), e3 = __expf(l3 - m);
        const float inv = 1.0f / (e0 + e1 + e2 + e3);
        aw[it][0] = e0 * inv; aw[it][1] = e1 * inv;
        aw[it][2] = e2 * inv; aw[it][3] = e3 * inv;
    }
    __syncthreads();   // scratch becomes the s tile

    // ---------------- 2b: bilinear gather from LDS halo -> s tile ----------------
    #pragma unroll
    for (int it = 0; it < 2; ++it) {
        const int item = it * 256 + tid;
        const int t = item >> 3, h = item & 7;
        const int qx = X + (t & 7), qy = Y + (t >> 3);
        const float cx = (float)qx * (128.0f / 127.0f);
        const float cy = (float)qy * (128.0f / 127.0f);

        f32x2 acc2[8];
        #pragma unroll
        for (int d = 0; d < 8; ++d) acc2[d] = (f32x2){0.f, 0.f};

        #pragma unroll
        for (int p = 0; p < 4; ++p) {
            const float px = cx + ox[it][p] - 0.5f;
            const float py = cy + oy[it][p] - 0.5f;
            const float fx = floorf(px), fy = floorf(py);
            const float wx = px - fx, wy = py - fy;
            const int xi = (int)fx, yi = (int)fy;
            const float cw[4] = {(1.f - wx) * (1.f - wy), wx * (1.f - wy),
                                 (1.f - wx) * wy,         wx * wy};
            const int hx0 = min(max(xi - HOX, 0), 10), hx1 = min(hx0 + 1, 10);
            const int hy0 = min(max(yi - HOY, 0), 10), hy1 = min(hy0 + 1, 10);
            const int cxs[4] = {hx0, hx1, hx0, hx1};
            const int cys[4] = {hy0, hy0, hy1, hy1};
            const int gxs[4] = {xi, xi + 1, xi, xi + 1};
            const int gys[4] = {yi, yi, yi + 1, yi + 1};
            #pragma unroll
            for (int c4 = 0; c4 < 4; ++c4) {
                const bool valid = (gxs[c4] >= 0) & (gxs[c4] < 128) &
                                   (gys[c4] >= 0) & (gys[c4] < 128);
                const float wgt = valid ? cw[c4] * aw[it][p] : 0.f;
                const int hp = cys[c4] * 11 + cxs[c4];
                const int col = (((h + hp) & 7)) * 16;
                const u32* vp = (const u32*)&vhalo[hp * 136 + col];
                u32x4 ra = *(const u32x4*)vp;
                u32x4 rb = *(const u32x4*)(vp + 4);
                const f32x2 w2 = {wgt, wgt};
                #pragma unroll
                for (int d = 0; d < 4; ++d) {
                    const u32 da = ra[d];
                    f32x2 v = {__uint_as_float(da << 16),
                               __uint_as_float(da & 0xffff0000u)};
                    acc2[d] += w2 * v;                       // v_pk_fma_f32
                }
                #pragma unroll
                for (int d = 0; d < 4; ++d) {
                    const u32 db = rb[d];
                    f32x2 v = {__uint_as_float(db << 16),
                               __uint_as_float(db & 0xffff0000u)};
                    acc2[4 + d] += w2 * v;
                }
            }
        }
        u32x4 s0, s1;
        #pragma unroll
        for (int d = 0; d < 4; ++d) {
            s0[d] = pk2bf(acc2[d].x, acc2[d].y);
            s1[d] = pk2bf(acc2[4 + d].x, acc2[4 + d].y);
        }
        *(u32x4*)&scratch[t * 136 + h * 16]     = s0;
        *(u32x4*)&scratch[t * 136 + h * 16 + 8] = s1;
    }
    __syncthreads();   // s tile ready; vhalo dead -> reuse as f32 stage

    // ---------------- 2c: out MFMA + bias -> staged f32, coalesced epilogue ----
    float* ostage = (float*)vhalo;   // 64 tokens x 128 f32 = 32768 B
    {
        bf16x8 afrag[4];
        #pragma unroll
        for (int kb = 0; kb < 4; ++kb)
            afrag[kb] = *(const bf16x8*)&scratch[(w * 16 + lane16) * 136 + kb * 32 + quad * 8];

        #pragma unroll
        for (int nt = 0; nt < 8; ++nt) {
            f32x4 acc = {0.f, 0.f, 0.f, 0.f};
            const bf16x8* bp = WfO + ((size_t)(nt * 4) * 4 + quad) * 16 + lane16;
            #pragma unroll
            for (int kb = 0; kb < 4; ++kb)
                acc = __builtin_amdgcn_mfma_f32_16x16x32_bf16(afrag[kb], bp[kb * 64], acc, 0, 0, 0);
            const int n = nt * 16 + lane16;
            const float bias = b_out[n];
            const int pcol = ((((n >> 2) + 2 * quad) & 31) << 2) + (n & 3);
            #pragma unroll
            for (int r = 0; r < 4; ++r)
                ostage[(w * 16 + quad * 4 + r) * 128 + pcol] = acc[r] + bias;
        }
    }
    __syncthreads();
    #pragma unroll
    for (int i = 0; i < 8; ++i) {
        const int tok = w * 16 + 2 * i + (l >> 5);
        const int p = l & 31;
        const int c = (p - 2 * ((i >> 1) & 3)) & 31;   // un-rotate
        f32x4 s = *(const f32x4*)&ostage[tok * 128 + p * 4];
        const size_t g = (batch_base + (size_t)(Y + (tok >> 3)) * 128 + (X + (tok & 7))) * 128
                         + (size_t)(c * 4);
        f32x4 q = *(const f32x4*)&query[g];
        f32x4 o;
        o.x = s.x + 2.0f * q.x; o.y = s.y + 2.0f * q.y;
        o.z = s.z + 2.0f * q.z; o.w = s.w + 2.0f * q.w;
        *(f32x4*)&out[g] = o;
    }
}

// ---------------------------------------------------------------------------
// Legacy fused kernel (R6, measured 47.5 us) — fallback if ws_size is too
// small for the prepass val buffer. Kept verbatim.
// ---------------------------------------------------------------------------
__global__ __launch_bounds__(256, 2)
void fused_legacy(const float* __restrict__ query,
                  const float* __restrict__ b_off, const float* __restrict__ b_attn,
                  const float* __restrict__ b_val, const float* __restrict__ b_out,
                  const u16* __restrict__ Wswz, const u16* __restrict__ Wout_swz,
                  float* __restrict__ out)
{
    __shared__ __align__(16) u16 vhalo[121 * 136];
    __shared__ __align__(16) u16 scratch[64 * 136 + 2048];

    const int tid = threadIdx.x;
    const int bid = blockIdx.x;
    const int b_  = bid >> 8;
    const int sq  = bid & 255;
    const int Y   = (sq >> 4) * 8;
    const int X   = (sq & 15) * 8;
    const int HOX = X - 2 + (X >> 6);
    const int HOY = Y - 2 + (Y >> 6);

    const int w = tid >> 6, l = tid & 63;
    const int lane16 = l & 15, quad = l >> 4;
    const size_t batch_base = (size_t)b_ * NQ;

    const bf16x8* Wf  = (const bf16x8*)Wswz;
    const bf16x8* WfO = (const bf16x8*)Wout_swz;

    {
        const int tl = w * 16 + lane16;
        const int ty = tl >> 3, tx = tl & 7;
        const size_t grow = batch_base + (size_t)(Y + ty) * 128 + (X + tx);
        const float* qrow = query + grow * 128 + quad * 8;
        bf16x8 afrag[4];
        #pragma unroll
        for (int kb = 0; kb < 4; ++kb)
            afrag[kb] = make_afrag(qrow + kb * 32);
        #pragma unroll
        for (int nt = 8; nt < 14; ++nt) {
            f32x4 acc = {0.f, 0.f, 0.f, 0.f};
            const bf16x8* bp = Wf + ((size_t)(nt * 4) * 4 + quad) * 16 + lane16;
            #pragma unroll
            for (int kb = 0; kb < 4; ++kb)
                acc = __builtin_amdgcn_mfma_f32_16x16x32_bf16(afrag[kb], bp[kb * 64], acc, 0, 0, 0);
            if (nt < 12) {
                const int c = (nt - 8) * 16 + lane16;
                const float bias = b_off[c];
                #pragma unroll
                for (int r = 0; r < 4; ++r)
                    scratch[(w * 16 + quad * 4 + r) * 96 + c] = f2bf(acc[r] + bias);
            } else {
                const int c = (nt - 12) * 16 + lane16;
                const float bias = b_attn[c];
                #pragma unroll
                for (int r = 0; r < 4; ++r)
                    scratch[(w * 16 + quad * 4 + r) * 96 + 64 + c] = f2bf(acc[r] + bias);
            }
        }
    }
    #pragma unroll
    for (int i = 0; i < 2; ++i) {
        const int a = w + 4 * i;
        int hp = a * 16 + lane16; if (hp > 120) hp = 120;
        const int hy = hp / 11, hx = hp - hy * 11;
        const int gy = min(max(HOY + hy, 0), 127);
        const int gx = min(max(HOX + hx, 0), 127);
        const float* qrow = query + (batch_base + (size_t)gy * 128 + gx) * 128 + quad * 8;
        bf16x8 afrag[4];
        #pragma unroll
        for (int kb = 0; kb < 4; ++kb)
            afrag[kb] = make_afrag(qrow + kb * 32);
        #pragma unroll
        for (int nt = 0; nt < 8; ++nt) {
            f32x4 acc = {0.f, 0.f, 0.f, 0.f};
            const bf16x8* bp = Wf + ((size_t)(nt * 4) * 4 + quad) * 16 + lane16;
            #pragma unroll
            for (int kb = 0; kb < 4; ++kb)
                acc = __builtin_amdgcn_mfma_f32_16x16x32_bf16(afrag[kb], bp[kb * 64], acc, 0, 0, 0);
            const float bias = b_val[nt * 16 + lane16];
            #pragma unroll
            for (int r = 0; r < 4; ++r) {
                int hpr = a * 16 + quad * 4 + r; if (hpr > 120) hpr = 120;
                const int col = ((nt + hpr) & 7) * 16 + lane16;
                vhalo[hpr * 136 + col] = f2bf(acc[r] + bias);
            }
        }
    }
    __syncthreads();

    float aw[2][4], ox[2][4], oy[2][4];
    #pragma unroll
    for (int it = 0; it < 2; ++it) {
        const int item = it * 256 + tid;
        const int t = item >> 3, h = item & 7;
        bf16x8 ofr = *(const bf16x8*)&scratch[t * 96 + h * 8];
        bf16x4 atr = *(const bf16x4*)&scratch[t * 96 + 64 + h * 4];
        #pragma unroll
        for (int p = 0; p < 4; ++p) {
            ox[it][p] = bf2f((u16)ofr[2 * p]);
            oy[it][p] = bf2f((u16)ofr[2 * p + 1]);
        }
        const float l0 = bf2f((u16)atr[0]), l1 = bf2f((u16)atr[1]);
        const float l2 = bf2f((u16)atr[2]), l3 = bf2f((u16)atr[3]);
        const float m = fmaxf(fmaxf(l0, l1), fmaxf(l2, l3));
        const float e0 = __expf(l0 - m), e1 = __expf(l1 - m);
        const float e2 = __expf(l2 - m), e3 = __expf(l3 - m);
        const float inv = 1.0f / (e0 + e1 + e2 + e3);
        aw[it][0] = e0 * inv; aw[it][1] = e1 * inv;
        aw[it][2] = e2 * inv; aw[it][3] = e3 * inv;
    }
    __syncthreads();

    #pragma unroll
    for (int it = 0; it < 2; ++it) {
        const int item = it * 256 + tid;
        const int t = item >> 3, h = item & 7;
        const int qx = X + (t & 7), qy = Y + (t >> 3);
        const float cx = (float)qx * (128.0f / 127.0f);
        const float cy = (float)qy * (128.0f / 127.0f);

        f32x2 acc2[8];
        #pragma unroll
        for (int d = 0; d < 8; ++d) acc2[d] = (f32x2){0.f, 0.f};

        #pragma unroll
        for (int p = 0; p < 4; ++p) {
            const float px = cx + ox[it][p] - 0.5f;
            const float py = cy + oy[it][p] - 0.5f;
            const float fx = floorf(px), fy = floorf(py);
            const float wx = px - fx, wy = py - fy;
            const int xi = (int)fx, yi = (int)fy;
            const float cw[4] = {(1.f - wx) * (1.f - wy), wx * (1.f - wy),
                                 (1.f - wx) * wy,         wx * wy};
            const int hx0 = min(max(xi - HOX, 0), 10), hx1 = min(hx0 + 1, 10);
            const int hy0 = min(max(yi - HOY, 0), 10), hy1 = min(hy0 + 1, 10);
            const int cxs[4] = {hx0, hx1, hx0, hx1};
            const int cys[4] = {hy0, hy0, hy1, hy1};
            const int gxs[4] = {xi, xi + 1, xi, xi + 1};
            const int gys[4] = {yi, yi, yi + 1, yi + 1};
            #pragma unroll
            for (int c4 = 0; c4 < 4; ++c4) {
                const bool valid = (gxs[c4] >= 0) & (gxs[c4] < 128) &
                                   (gys[c4] >= 0) & (gys[c4] < 128);
                const float wgt = valid ? cw[c4] * aw[it][p] : 0.f;
                const int hp = cys[c4] * 11 + cxs[c4];
                const int col = (((h + hp) & 7)) * 16;
                const u32* vp = (const u32*)&vhalo[hp * 136 + col];
                u32x4 ra = *(const u32x4*)vp;
                u32x4 rb = *(const u32x4*)(vp + 4);
                const f32x2 w2 = {wgt, wgt};
                #pragma unroll
                for (int d = 0; d < 4; ++d) {
                    const u32 da = ra[d];
                    f32x2 v = {__uint_as_float(da << 16),
                               __uint_as_float(da & 0xffff0000u)};
                    acc2[d] += w2 * v;
                }
                #pragma unroll
                for (int d = 0; d < 4; ++d) {
                    const u32 db = rb[d];
                    f32x2 v = {__uint_as_float(db << 16),
                               __uint_as_float(db & 0xffff0000u)};
                    acc2[4 + d] += w2 * v;
                }
            }
        }
        u32x4 s0, s1;
        #pragma unroll
        for (int d = 0; d < 4; ++d) {
            s0[d] = pk2bf(acc2[d].x, acc2[d].y);
            s1[d] = pk2bf(acc2[4 + d].x, acc2[4 + d].y);
        }
        *(u32x4*)&scratch[t * 136 + h * 16]     = s0;
        *(u32x4*)&scratch[t * 136 + h * 16 + 8] = s1;
    }
    __syncthreads();

    float* ostage = (float*)vhalo;
    {
        bf16x8 afrag[4];
        #pragma unroll
        for (int kb = 0; kb < 4; ++kb)
            afrag[kb] = *(const bf16x8*)&scratch[(w * 16 + lane16) * 136 + kb * 32 + quad * 8];

        #pragma unroll
        for (int nt = 0; nt < 8; ++nt) {
            f32x4 acc = {0.f, 0.f, 0.f, 0.f};
            const bf16x8* bp = WfO + ((size_t)(nt * 4) * 4 + quad) * 16 + lane16;
            #pragma unroll
            for (int kb = 0; kb < 4; ++kb)
                acc = __builtin_amdgcn_mfma_f32_16x16x32_bf16(afrag[kb], bp[kb * 64], acc, 0, 0, 0);
            const int n = nt * 16 + lane16;
            const float bias = b_out[n];
            const int pcol = ((((n >> 2) + 2 * quad) & 31) << 2) + (n & 3);
            #pragma unroll
            for (int r = 0; r < 4; ++r)
                ostage[(w * 16 + quad * 4 + r) * 128 + pcol] = acc[r] + bias;
        }
    }
    __syncthreads();
    #pragma unroll
    for (int i = 0; i < 8; ++i) {
        const int tok = w * 16 + 2 * i + (l >> 5);
        const int p = l & 31;
        const int c = (p - 2 * ((i >> 1) & 3)) & 31;
        f32x4 s = *(const f32x4*)&ostage[tok * 128 + p * 4];
        const size_t g = (batch_base + (size_t)(Y + (tok >> 3)) * 128 + (X + (tok & 7))) * 128
                         + (size_t)(c * 4);
        f32x4 q = *(const f32x4*)&query[g];
        f32x4 o;
        o.x = s.x + 2.0f * q.x; o.y = s.y + 2.0f * q.y;
        o.z = s.z + 2.0f * q.z; o.w = s.w + 2.0f * q.w;
        *(f32x4*)&out[g] = o;
    }
}

extern "C" void kernel_launch(void* const* d_in, const int* in_sizes, int n_in,
                              void* d_out, int out_size, void* d_ws, size_t ws_size,
                              hipStream_t stream)
{
    const float* query  = (const float*)d_in[0];
    const float* W_off  = (const float*)d_in[1];
    const float* b_off  = (const float*)d_in[2];
    const float* W_attn = (const float*)d_in[3];
    const float* b_attn = (const float*)d_in[4];
    const float* W_val  = (const float*)d_in[5];
    const float* b_val  = (const float*)d_in[6];
    const float* W_out  = (const float*)d_in[7];
    const float* b_out  = (const float*)d_in[8];
    float* out = (float*)d_out;

    u16* Wswz     = (u16*)d_ws;                      // [0, 57344)
    u16* Wout_swz = (u16*)((char*)d_ws + 57344);     // [57344, 90112)

    // Prepass buffer: val bf16 [65536][128] (16 MB) at 128 KB alignment.
    const size_t OFF_VAL = 131072;
    const size_t WS_NEED = OFF_VAL + (size_t)GTOK * 128 * 2;

    setup_kernel<<<176, 256, 0, stream>>>(W_val, W_off, W_attn, W_out, Wswz, Wout_swz);

    if (ws_size >= WS_NEED) {
        u16* val = (u16*)((char*)d_ws + OFF_VAL);
        prepass_kernel<<<1024, 256, 0, stream>>>(query, b_val, Wswz, val);
        fused_kernel<<<1024, 256, 0, stream>>>(query, b_off, b_attn, b_out,
                                               Wswz, Wout_swz, val, out);
    } else {
        fused_legacy<<<1024, 256, 0, stream>>>(query, b_off, b_attn, b_val, b_out,
                                               Wswz, Wout_swz, out);
    }
}

// Round 10
// 129.447 us; speedup vs baseline: 1.0196x; 1.0196x over previous
//
#include <hip/hip_runtime.h>

#define BS 4
#define NQ 16384
#define GTOK 65536   // BS * NQ

typedef unsigned short u16;
typedef unsigned int u32;
typedef __attribute__((ext_vector_type(8))) short bf16x8;   // 8 bf16 (4 VGPRs)
typedef __attribute__((ext_vector_type(4))) short bf16x4;   // 4 bf16
typedef __attribute__((ext_vector_type(4))) float f32x4;
typedef __attribute__((ext_vector_type(2))) float f32x2;
typedef __attribute__((ext_vector_type(4))) unsigned int u32x4;

__device__ __forceinline__ float bf2f(u16 v) { return __uint_as_float(((u32)v) << 16); }
__device__ __forceinline__ u16 f2bf(float f) {
    u32 u = __float_as_uint(f);
    u32 r = (u + 0x7fffu + ((u >> 16) & 1u)) >> 16;   // RNE, finite inputs only
    return (u16)r;
}
// NOTE (R5 post-mortem): inline-asm v_cvt_pk_bf16_f32 measured -42% on the
// fused kernel (reproduces learn_hip m240's -37%). Keep the bit-twiddle.
__device__ __forceinline__ u32 pk2bf(float lo, float hi) {
    return (u32)f2bf(lo) | ((u32)f2bf(hi) << 16);
}
// Build an MFMA A-frag (8 bf16) from 8 contiguous f32.
__device__ __forceinline__ bf16x8 make_afrag(const float* qrow) {
    f32x4 q0 = *(const f32x4*)(qrow);
    f32x4 q1 = *(const f32x4*)(qrow + 4);
    union { bf16x8 v; u32 u[4]; } a;
    a.u[0] = pk2bf(q0.x, q0.y); a.u[1] = pk2bf(q0.z, q0.w);
    a.u[2] = pk2bf(q1.x, q1.y); a.u[3] = pk2bf(q1.z, q1.w);
    return a.v;
}

// ---------------------------------------------------------------------------
// Setup: swizzle weights into MFMA B-frag order (bf16).
// B-frag: b[j] = B[k = kb*32 + quad*8 + j][n = nt*16 + lane16], flat index
// (((nt*4+kb)*4+quad)*16 + lane16)*8 + j.
// Proj B = [W_val | W_off | W_attn] (128 x 224): nt 0..13. W_out: nt 0..7.
// ---------------------------------------------------------------------------
__global__ __launch_bounds__(256)
void setup_kernel(const float* __restrict__ W_val, const float* __restrict__ W_off,
                  const float* __restrict__ W_attn, const float* __restrict__ W_out,
                  u16* __restrict__ Wswz, u16* __restrict__ Wout_swz)
{
    const int i = blockIdx.x * 256 + threadIdx.x;
    if (i < 28672) {                       // proj swizzle (14 nt)
        const int j = i & 7, lane = (i >> 3) & 15, quad = (i >> 7) & 3;
        const int kb = (i >> 9) & 3, nt = i >> 11;
        const int k = kb * 32 + quad * 8 + j;
        const int n = nt * 16 + lane;
        float v;
        if (n < 128)      v = W_val[k * 128 + n];
        else if (n < 192) v = W_off[k * 64 + (n - 128)];
        else              v = W_attn[k * 32 + (n - 192)];
        Wswz[i] = f2bf(v);
    } else if (i < 45056) {                // W_out swizzle (8 nt)
        const int i2 = i - 28672;
        const int j = i2 & 7, lane = (i2 >> 3) & 15, quad = (i2 >> 7) & 3;
        const int kb = (i2 >> 9) & 3, nt = i2 >> 11;
        const int k = kb * 32 + quad * 8 + j;
        const int n = nt * 16 + lane;
        Wout_swz[i2] = f2bf(W_out[k * 128 + n]);
    }
}

// ---------------------------------------------------------------------------
// Pre-pass: all three projections for ALL 65536 tokens as one streaming GEMM.
// R9 lesson: keeping off/attn OUT of the fused kernel matters — re-adding the
// query-read projection phase to the occ-3 fused kernel regressed it 43->62 us
// (R3's {query f32 reads x 3 blocks/CU} latency toxicity, reproduced). The
// 24 MB off/attn HBM round-trip is cheaper than that phase.
// ---------------------------------------------------------------------------
__global__ __launch_bounds__(256)
void prepass_kernel(const float* __restrict__ query,
                    const float* __restrict__ b_off, const float* __restrict__ b_attn,
                    const float* __restrict__ b_val,
                    const u16* __restrict__ Wswz,
                    u16* __restrict__ val, u16* __restrict__ offattn)
{
    __shared__ __align__(16) u16 stage[64 * 136];   // 17408 B: val stage, then oa stage
    const int tid = threadIdx.x;
    const int w = tid >> 6, l = tid & 63;
    const int lane16 = l & 15, quad = l >> 4;
    const int gtok0 = blockIdx.x * 64;
    const bf16x8* Wf = (const bf16x8*)Wswz;

    // A-frags for this wave's 16 tokens
    const int tl = w * 16 + lane16;
    const float* qrow = query + (size_t)(gtok0 + tl) * 128 + quad * 8;
    bf16x8 afrag[4];
    #pragma unroll
    for (int kb = 0; kb < 4; ++kb)
        afrag[kb] = make_afrag(qrow + kb * 32);

    // val: nt 0..7 -> stage rows stride 136 (quad-group writes are 2-way = free)
    #pragma unroll
    for (int nt = 0; nt < 8; ++nt) {
        f32x4 acc = {0.f, 0.f, 0.f, 0.f};
        const bf16x8* bp = Wf + ((size_t)(nt * 4) * 4 + quad) * 16 + lane16;
        #pragma unroll
        for (int kb = 0; kb < 4; ++kb)
            acc = __builtin_amdgcn_mfma_f32_16x16x32_bf16(afrag[kb], bp[kb * 64], acc, 0, 0, 0);
        const float bias = b_val[nt * 16 + lane16];
        #pragma unroll
        for (int r = 0; r < 4; ++r)
            stage[(w * 16 + quad * 4 + r) * 136 + nt * 16 + lane16] = f2bf(acc[r] + bias);
    }
    // off/attn: nt 8..13 -> keep in regs until stage is free
    f32x4 oacc[6];
    #pragma unroll
    for (int j = 0; j < 6; ++j) {
        const int nt = 8 + j;
        f32x4 acc = {0.f, 0.f, 0.f, 0.f};
        const bf16x8* bp = Wf + ((size_t)(nt * 4) * 4 + quad) * 16 + lane16;
        #pragma unroll
        for (int kb = 0; kb < 4; ++kb)
            acc = __builtin_amdgcn_mfma_f32_16x16x32_bf16(afrag[kb], bp[kb * 64], acc, 0, 0, 0);
        oacc[j] = acc;
    }
    __syncthreads();
    // val readback: 64 rows x 16 chunks of 16 B, coalesced full-line stores
    #pragma unroll
    for (int i = 0; i < 4; ++i) {
        const int chunk = i * 256 + tid;          // 0..1023
        const int t = chunk >> 4, c16 = chunk & 15;
        u32x4 v = *(const u32x4*)&stage[t * 136 + c16 * 8];
        *(u32x4*)&val[(size_t)(gtok0 + t) * 128 + c16 * 8] = v;
    }
    __syncthreads();
    // oa stage: rows stride 104 (2-way bank aliasing = free)
    #pragma unroll
    for (int j = 0; j < 6; ++j) {
        const int c = j * 16 + lane16;            // 0..95
        const float bias = (c < 64) ? b_off[c] : b_attn[c - 64];
        #pragma unroll
        for (int r = 0; r < 4; ++r)
            stage[(w * 16 + quad * 4 + r) * 104 + c] = f2bf(oacc[j][r] + bias);
    }
    __syncthreads();
    // oa readback: 64 rows x 12 chunks of 16 B
    #pragma unroll
    for (int i = 0; i < 3; ++i) {
        const int chunk = i * 256 + tid;          // 0..767
        const int t = chunk / 12, cj = chunk - t * 12;
        u32x4 v = *(const u32x4*)&stage[t * 104 + cj * 8];
        *(u32x4*)&offattn[(size_t)(gtok0 + t) * 96 + cj * 8] = v;
    }
}

// ---------------------------------------------------------------------------
// Fused kernel (prepass variant): block = 8x8 token square + 11x11 val halo.
// Halo recentred: origin (X-2+(X>>6), Y-2+(Y>>6)) tracks the +1 px drift of
// cx = qx*128/127; >=1 px (4.4 sigma) margin; out-of-grid corners masked.
// 3 blocks/CU is fine HERE (R8 measured fast): no query-read projection phase
// remains in this kernel — all global reads are bf16 val/offattn (small, L2-
// friendly) + the coalesced epilogue. Do NOT re-add a query MFMA phase (R9:
// 43->62 us).
//   L1: own-token off/attn bf16 -> scratch (stride 96), coalesced
//   L2: halo val bf16 -> vhalo (stride 136, head swizzle), coalesced
//   2a: softmax -> regs; 2b: bilinear gather (pk_fma) -> s tile;
//   2c: out MFMA + bias -> f32 stage in vhalo, coalesced full-line epilogue
//       with the 2*query residual (query read ONLY here).
// C/D layout: col = lane&15, row = quad*4 + reg  [measured m89].
// ---------------------------------------------------------------------------
__global__ __launch_bounds__(256, 3)
void fused_kernel(const float* __restrict__ query,
                  const float* __restrict__ b_out,
                  const u16* __restrict__ Wout_swz,
                  const u16* __restrict__ val, const u16* __restrict__ offattn,
                  float* __restrict__ out)
{
    __shared__ __align__(16) u16 vhalo[121 * 136];   // 32912 B (also 2c f32 stage)
    __shared__ __align__(16) u16 scratch[64 * 136];  // 17408 B (off/attn then s tile)

    const int tid = threadIdx.x;
    const int bid = blockIdx.x;
    const int b_  = bid >> 8;          // batch
    const int sq  = bid & 255;
    const int Y   = (sq >> 4) * 8;
    const int X   = (sq & 15) * 8;
    const int HOX = X - 2 + (X >> 6);  // halo origin (recentred)
    const int HOY = Y - 2 + (Y >> 6);

    const int w = tid >> 6, l = tid & 63;
    const int lane16 = l & 15, quad = l >> 4;
    const size_t batch_base = (size_t)b_ * NQ;

    const bf16x8* WfO = (const bf16x8*)Wout_swz;

    // ---------------- L1: own-token off/attn -> scratch (64 x 96 u16) ----------
    #pragma unroll
    for (int i = 0; i < 3; ++i) {
        const int chunk = i * 256 + tid;          // 0..767
        const int t = chunk / 12, cj = chunk - t * 12;
        const size_t gt = batch_base + (size_t)(Y + (t >> 3)) * 128 + (X + (t & 7));
        u32x4 v = *(const u32x4*)&offattn[gt * 96 + cj * 8];
        *(u32x4*)&scratch[t * 96 + cj * 8] = v;
    }
    // ---------------- L2: halo val -> vhalo (swizzled) -------------------------
    #pragma unroll
    for (int i = 0; i < 8; ++i) {
        const int chunk = i * 256 + tid;          // 0..2047, use 0..1935
        if (chunk < 1936) {
            const int hp = chunk >> 4, c16 = chunk & 15;
            const int hy = hp / 11, hx = hp - hy * 11;
            const int gy = min(max(HOY + hy, 0), 127);
            const int gx = min(max(HOX + hx, 0), 127);
            const size_t gt = batch_base + (size_t)gy * 128 + gx;
            u32x4 v = *(const u32x4*)&val[gt * 128 + c16 * 8];
            const int col = ((((c16 >> 1) + hp) & 7) << 4) + ((c16 & 1) << 3);
            *(u32x4*)&vhalo[hp * 136 + col] = v;
        }
    }
    __syncthreads();

    // ---------------- 2a: off/attn -> regs (softmax over 4 pts) ----------------
    float aw[2][4], ox[2][4], oy[2][4];
    #pragma unroll
    for (int it = 0; it < 2; ++it) {
        const int item = it * 256 + tid;
        const int t = item >> 3, h = item & 7;
        bf16x8 ofr = *(const bf16x8*)&scratch[t * 96 + h * 8];
        bf16x4 atr = *(const bf16x4*)&scratch[t * 96 + 64 + h * 4];
        #pragma unroll
        for (int p = 0; p < 4; ++p) {
            ox[it][p] = bf2f((u16)ofr[2 * p]);
            oy[it][p] = bf2f((u16)ofr[2 * p + 1]);
        }
        const float l0 = bf2f((u16)atr[0]), l1 = bf2f((u16)atr[1]);
        const float l2 = bf2f((u16)atr[2]), l3 = bf2f((u16)atr[3]);
        const float m = fmaxf(fmaxf(l0, l1), fmaxf(l2, l3));
        const float e0 = __expf(l0 - m), e1 = __expf(l1 - m);
        const float e2 = __expf(l2 - m), e3 = __expf(l3 - m);
        const float inv = 1.0f / (e0 + e1 + e2 + e3);
        aw[it][0] = e0 * inv; aw[it][1] = e1 * inv;
        aw[it][2] = e2 * inv; aw[it][3] = e3 * inv;
    }
    __syncthreads();   // scratch becomes the s tile

    // ---------------- 2b: bilinear gather from LDS halo -> s tile ----------------
    #pragma unroll
    for (int it = 0; it < 2; ++it) {
        const int item = it * 256 + tid;
        const int t = item >> 3, h = item & 7;
        const int qx = X + (t & 7), qy = Y + (t >> 3);
        const float cx = (float)qx * (128.0f / 127.0f);
        const float cy = (float)qy * (128.0f / 127.0f);

        f32x2 acc2[8];
        #pragma unroll
        for (int d = 0; d < 8; ++d) acc2[d] = (f32x2){0.f, 0.f};

        #pragma unroll
        for (int p = 0; p < 4; ++p) {
            const float px = cx + ox[it][p] - 0.5f;
            const float py = cy + oy[it][p] - 0.5f;
            const float fx = floorf(px), fy = floorf(py);
            const float wx = px - fx, wy = py - fy;
            const int xi = (int)fx, yi = (int)fy;
            const float cw[4] = {(1.f - wx) * (1.f - wy), wx * (1.f - wy),
                                 (1.f - wx) * wy,         wx * wy};
            const int hx0 = min(max(xi - HOX, 0), 10), hx1 = min(hx0 + 1, 10);
            const int hy0 = min(max(yi - HOY, 0), 10), hy1 = min(hy0 + 1, 10);
            const int cxs[4] = {hx0, hx1, hx0, hx1};
            const int cys[4] = {hy0, hy0, hy1, hy1};
            const int gxs[4] = {xi, xi + 1, xi, xi + 1};
            const int gys[4] = {yi, yi, yi + 1, yi + 1};
            #pragma unroll
            for (int c4 = 0; c4 < 4; ++c4) {
                const bool valid = (gxs[c4] >= 0) & (gxs[c4] < 128) &
                                   (gys[c4] >= 0) & (gys[c4] < 128);
                const float wgt = valid ? cw[c4] * aw[it][p] : 0.f;
                const int hp = cys[c4] * 11 + cxs[c4];
                const int col = (((h + hp) & 7)) * 16;
                const u32* vp = (const u32*)&vhalo[hp * 136 + col];
                u32x4 ra = *(const u32x4*)vp;
                u32x4 rb = *(const u32x4*)(vp + 4);
                const f32x2 w2 = {wgt, wgt};
                #pragma unroll
                for (int d = 0; d < 4; ++d) {
                    const u32 da = ra[d];
                    f32x2 v = {__uint_as_float(da << 16),
                               __uint_as_float(da & 0xffff0000u)};
                    acc2[d] += w2 * v;                       // v_pk_fma_f32
                }
                #pragma unroll
                for (int d = 0; d < 4; ++d) {
                    const u32 db = rb[d];
                    f32x2 v = {__uint_as_float(db << 16),
                               __uint_as_float(db & 0xffff0000u)};
                    acc2[4 + d] += w2 * v;
                }
            }
        }
        u32x4 s0, s1;
        #pragma unroll
        for (int d = 0; d < 4; ++d) {
            s0[d] = pk2bf(acc2[d].x, acc2[d].y);
            s1[d] = pk2bf(acc2[4 + d].x, acc2[4 + d].y);
        }
        *(u32x4*)&scratch[t * 136 + h * 16]     = s0;
        *(u32x4*)&scratch[t * 136 + h * 16 + 8] = s1;
    }
    __syncthreads();   // s tile ready; vhalo dead -> reuse as f32 stage

    // ---------------- 2c: out MFMA + bias -> staged f32, coalesced epilogue ----
    float* ostage = (float*)vhalo;   // 64 tokens x 128 f32 = 32768 B
    {
        bf16x8 afrag[4];
        #pragma unroll
        for (int kb = 0; kb < 4; ++kb)
            afrag[kb] = *(const bf16x8*)&scratch[(w * 16 + lane16) * 136 + kb * 32 + quad * 8];

        #pragma unroll
        for (int nt = 0; nt < 8; ++nt) {
            f32x4 acc = {0.f, 0.f, 0.f, 0.f};
            const bf16x8* bp = WfO + ((size_t)(nt * 4) * 4 + quad) * 16 + lane16;
            #pragma unroll
            for (int kb = 0; kb < 4; ++kb)
                acc = __builtin_amdgcn_mfma_f32_16x16x32_bf16(afrag[kb], bp[kb * 64], acc, 0, 0, 0);
            const int n = nt * 16 + lane16;
            const float bias = b_out[n];
            const int pcol = ((((n >> 2) + 2 * quad) & 31) << 2) + (n & 3);
            #pragma unroll
            for (int r = 0; r < 4; ++r)
                ostage[(w * 16 + quad * 4 + r) * 128 + pcol] = acc[r] + bias;
        }
    }
    __syncthreads();
    #pragma unroll
    for (int i = 0; i < 8; ++i) {
        const int tok = w * 16 + 2 * i + (l >> 5);
        const int p = l & 31;
        const int c = (p - 2 * ((i >> 1) & 3)) & 31;   // un-rotate
        f32x4 s = *(const f32x4*)&ostage[tok * 128 + p * 4];
        const size_t g = (batch_base + (size_t)(Y + (tok >> 3)) * 128 + (X + (tok & 7))) * 128
                         + (size_t)(c * 4);
        f32x4 q = *(const f32x4*)&query[g];
        f32x4 o;
        o.x = s.x + 2.0f * q.x; o.y = s.y + 2.0f * q.y;
        o.z = s.z + 2.0f * q.z; o.w = s.w + 2.0f * q.w;
        *(f32x4*)&out[g] = o;
    }
}

// ---------------------------------------------------------------------------
// Legacy fused kernel (R6, measured 47.5 us) — fallback if ws_size is too
// small for the prepass buffers. Kept verbatim.
// ---------------------------------------------------------------------------
__global__ __launch_bounds__(256, 2)
void fused_legacy(const float* __restrict__ query,
                  const float* __restrict__ b_off, const float* __restrict__ b_attn,
                  const float* __restrict__ b_val, const float* __restrict__ b_out,
                  const u16* __restrict__ Wswz, const u16* __restrict__ Wout_swz,
                  float* __restrict__ out)
{
    __shared__ __align__(16) u16 vhalo[121 * 136];
    __shared__ __align__(16) u16 scratch[64 * 136 + 2048];

    const int tid = threadIdx.x;
    const int bid = blockIdx.x;
    const int b_  = bid >> 8;
    const int sq  = bid & 255;
    const int Y   = (sq >> 4) * 8;
    const int X   = (sq & 15) * 8;
    const int HOX = X - 2 + (X >> 6);
    const int HOY = Y - 2 + (Y >> 6);

    const int w = tid >> 6, l = tid & 63;
    const int lane16 = l & 15, quad = l >> 4;
    const size_t batch_base = (size_t)b_ * NQ;

    const bf16x8* Wf  = (const bf16x8*)Wswz;
    const bf16x8* WfO = (const bf16x8*)Wout_swz;

    {
        const int tl = w * 16 + lane16;
        const int ty = tl >> 3, tx = tl & 7;
        const size_t grow = batch_base + (size_t)(Y + ty) * 128 + (X + tx);
        const float* qrow = query + grow * 128 + quad * 8;
        bf16x8 afrag[4];
        #pragma unroll
        for (int kb = 0; kb < 4; ++kb)
            afrag[kb] = make_afrag(qrow + kb * 32);
        #pragma unroll
        for (int nt = 8; nt < 14; ++nt) {
            f32x4 acc = {0.f, 0.f, 0.f, 0.f};
            const bf16x8* bp = Wf + ((size_t)(nt * 4) * 4 + quad) * 16 + lane16;
            #pragma unroll
            for (int kb = 0; kb < 4; ++kb)
                acc = __builtin_amdgcn_mfma_f32_16x16x32_bf16(afrag[kb], bp[kb * 64], acc, 0, 0, 0);
            if (nt < 12) {
                const int c = (nt - 8) * 16 + lane16;
                const float bias = b_off[c];
                #pragma unroll
                for (int r = 0; r < 4; ++r)
                    scratch[(w * 16 + quad * 4 + r) * 96 + c] = f2bf(acc[r] + bias);
            } else {
                const int c = (nt - 12) * 16 + lane16;
                const float bias = b_attn[c];
                #pragma unroll
                for (int r = 0; r < 4; ++r)
                    scratch[(w * 16 + quad * 4 + r) * 96 + 64 + c] = f2bf(acc[r] + bias);
            }
        }
    }
    #pragma unroll
    for (int i = 0; i < 2; ++i) {
        const int a = w + 4 * i;
        int hp = a * 16 + lane16; if (hp > 120) hp = 120;
        const int hy = hp / 11, hx = hp - hy * 11;
        const int gy = min(max(HOY + hy, 0), 127);
        const int gx = min(max(HOX + hx, 0), 127);
        const float* qrow = query + (batch_base + (size_t)gy * 128 + gx) * 128 + quad * 8;
        bf16x8 afrag[4];
        #pragma unroll
        for (int kb = 0; kb < 4; ++kb)
            afrag[kb] = make_afrag(qrow + kb * 32);
        #pragma unroll
        for (int nt = 0; nt < 8; ++nt) {
            f32x4 acc = {0.f, 0.f, 0.f, 0.f};
            const bf16x8* bp = Wf + ((size_t)(nt * 4) * 4 + quad) * 16 + lane16;
            #pragma unroll
            for (int kb = 0; kb < 4; ++kb)
                acc = __builtin_amdgcn_mfma_f32_16x16x32_bf16(afrag[kb], bp[kb * 64], acc, 0, 0, 0);
            const float bias = b_val[nt * 16 + lane16];
            #pragma unroll
            for (int r = 0; r < 4; ++r) {
                int hpr = a * 16 + quad * 4 + r; if (hpr > 120) hpr = 120;
                const int col = ((nt + hpr) & 7) * 16 + lane16;
                vhalo[hpr * 136 + col] = f2bf(acc[r] + bias);
            }
        }
    }
    __syncthreads();

    float aw[2][4], ox[2][4], oy[2][4];
    #pragma unroll
    for (int it = 0; it < 2; ++it) {
        const int item = it * 256 + tid;
        const int t = item >> 3, h = item & 7;
        bf16x8 ofr = *(const bf16x8*)&scratch[t * 96 + h * 8];
        bf16x4 atr = *(const bf16x4*)&scratch[t * 96 + 64 + h * 4];
        #pragma unroll
        for (int p = 0; p < 4; ++p) {
            ox[it][p] = bf2f((u16)ofr[2 * p]);
            oy[it][p] = bf2f((u16)ofr[2 * p + 1]);
        }
        const float l0 = bf2f((u16)atr[0]), l1 = bf2f((u16)atr[1]);
        const float l2 = bf2f((u16)atr[2]), l3 = bf2f((u16)atr[3]);
        const float m = fmaxf(fmaxf(l0, l1), fmaxf(l2, l3));
        const float e0 = __expf(l0 - m), e1 = __expf(l1 - m);
        const float e2 = __expf(l2 - m), e3 = __expf(l3 - m);
        const float inv = 1.0f / (e0 + e1 + e2 + e3);
        aw[it][0] = e0 * inv; aw[it][1] = e1 * inv;
        aw[it][2] = e2 * inv; aw[it][3] = e3 * inv;
    }
    __syncthreads();

    #pragma unroll
    for (int it = 0; it < 2; ++it) {
        const int item = it * 256 + tid;
        const int t = item >> 3, h = item & 7;
        const int qx = X + (t & 7), qy = Y + (t >> 3);
        const float cx = (float)qx * (128.0f / 127.0f);
        const float cy = (float)qy * (128.0f / 127.0f);

        f32x2 acc2[8];
        #pragma unroll
        for (int d = 0; d < 8; ++d) acc2[d] = (f32x2){0.f, 0.f};

        #pragma unroll
        for (int p = 0; p < 4; ++p) {
            const float px = cx + ox[it][p] - 0.5f;
            const float py = cy + oy[it][p] - 0.5f;
            const float fx = floorf(px), fy = floorf(py);
            const float wx = px - fx, wy = py - fy;
            const int xi = (int)fx, yi = (int)fy;
            const float cw[4] = {(1.f - wx) * (1.f - wy), wx * (1.f - wy),
                                 (1.f - wx) * wy,         wx * wy};
            const int hx0 = min(max(xi - HOX, 0), 10), hx1 = min(hx0 + 1, 10);
            const int hy0 = min(max(yi - HOY, 0), 10), hy1 = min(hy0 + 1, 10);
            const int cxs[4] = {hx0, hx1, hx0, hx1};
            const int cys[4] = {hy0, hy0, hy1, hy1};
            const int gxs[4] = {xi, xi + 1, xi, xi + 1};
            const int gys[4] = {yi, yi, yi + 1, yi + 1};
            #pragma unroll
            for (int c4 = 0; c4 < 4; ++c4) {
                const bool valid = (gxs[c4] >= 0) & (gxs[c4] < 128) &
                                   (gys[c4] >= 0) & (gys[c4] < 128);
                const float wgt = valid ? cw[c4] * aw[it][p] : 0.f;
                const int hp = cys[c4] * 11 + cxs[c4];
                const int col = (((h + hp) & 7)) * 16;
                const u32* vp = (const u32*)&vhalo[hp * 136 + col];
                u32x4 ra = *(const u32x4*)vp;
                u32x4 rb = *(const u32x4*)(vp + 4);
                const f32x2 w2 = {wgt, wgt};
                #pragma unroll
                for (int d = 0; d < 4; ++d) {
                    const u32 da = ra[d];
                    f32x2 v = {__uint_as_float(da << 16),
                               __uint_as_float(da & 0xffff0000u)};
                    acc2[d] += w2 * v;
                }
                #pragma unroll
                for (int d = 0; d < 4; ++d) {
                    const u32 db = rb[d];
                    f32x2 v = {__uint_as_float(db << 16),
                               __uint_as_float(db & 0xffff0000u)};
                    acc2[4 + d] += w2 * v;
                }
            }
        }
        u32x4 s0, s1;
        #pragma unroll
        for (int d = 0; d < 4; ++d) {
            s0[d] = pk2bf(acc2[d].x, acc2[d].y);
            s1[d] = pk2bf(acc2[4 + d].x, acc2[4 + d].y);
        }
        *(u32x4*)&scratch[t * 136 + h * 16]     = s0;
        *(u32x4*)&scratch[t * 136 + h * 16 + 8] = s1;
    }
    __syncthreads();

    float* ostage = (float*)vhalo;
    {
        bf16x8 afrag[4];
        #pragma unroll
        for (int kb = 0; kb < 4; ++kb)
            afrag[kb] = *(const bf16x8*)&scratch[(w * 16 + lane16) * 136 + kb * 32 + quad * 8];

        #pragma unroll
        for (int nt = 0; nt < 8; ++nt) {
            f32x4 acc = {0.f, 0.f, 0.f, 0.f};
            const bf16x8* bp = WfO + ((size_t)(nt * 4) * 4 + quad) * 16 + lane16;
            #pragma unroll
            for (int kb = 0; kb < 4; ++kb)
                acc = __builtin_amdgcn_mfma_f32_16x16x32_bf16(afrag[kb], bp[kb * 64], acc, 0, 0, 0);
            const int n = nt * 16 + lane16;
            const float bias = b_out[n];
            const int pcol = ((((n >> 2) + 2 * quad) & 31) << 2) + (n & 3);
            #pragma unroll
            for (int r = 0; r < 4; ++r)
                ostage[(w * 16 + quad * 4 + r) * 128 + pcol] = acc[r] + bias;
        }
    }
    __syncthreads();
    #pragma unroll
    for (int i = 0; i < 8; ++i) {
        const int tok = w * 16 + 2 * i + (l >> 5);
        const int p = l & 31;
        const int c = (p - 2 * ((i >> 1) & 3)) & 31;
        f32x4 s = *(const f32x4*)&ostage[tok * 128 + p * 4];
        const size_t g = (batch_base + (size_t)(Y + (tok >> 3)) * 128 + (X + (tok & 7))) * 128
                         + (size_t)(c * 4);
        f32x4 q = *(const f32x4*)&query[g];
        f32x4 o;
        o.x = s.x + 2.0f * q.x; o.y = s.y + 2.0f * q.y;
        o.z = s.z + 2.0f * q.z; o.w = s.w + 2.0f * q.w;
        *(f32x4*)&out[g] = o;
    }
}

extern "C" void kernel_launch(void* const* d_in, const int* in_sizes, int n_in,
                              void* d_out, int out_size, void* d_ws, size_t ws_size,
                              hipStream_t stream)
{
    const float* query  = (const float*)d_in[0];
    const float* W_off  = (const float*)d_in[1];
    const float* b_off  = (const float*)d_in[2];
    const float* W_attn = (const float*)d_in[3];
    const float* b_attn = (const float*)d_in[4];
    const float* W_val  = (const float*)d_in[5];
    const float* b_val  = (const float*)d_in[6];
    const float* W_out  = (const float*)d_in[7];
    const float* b_out  = (const float*)d_in[8];
    float* out = (float*)d_out;

    u16* Wswz     = (u16*)d_ws;                      // [0, 57344)
    u16* Wout_swz = (u16*)((char*)d_ws + 57344);     // [57344, 90112)

    // Prepass buffers: val bf16 [65536][128] (16 MB) + offattn bf16 [65536][96]
    // (12 MB), placed at 128 KB alignment. Total need ~29.5 MB.
    const size_t OFF_VAL = 131072;
    const size_t OFF_OA  = OFF_VAL + (size_t)GTOK * 128 * 2;
    const size_t WS_NEED = OFF_OA + (size_t)GTOK * 96 * 2;

    setup_kernel<<<176, 256, 0, stream>>>(W_val, W_off, W_attn, W_out, Wswz, Wout_swz);

    if (ws_size >= WS_NEED) {
        u16* val = (u16*)((char*)d_ws + OFF_VAL);
        u16* oa  = (u16*)((char*)d_ws + OFF_OA);
        prepass_kernel<<<1024, 256, 0, stream>>>(query, b_off, b_attn, b_val,
                                                 Wswz, val, oa);
        fused_kernel<<<1024, 256, 0, stream>>>(query, b_out, Wout_swz, val, oa, out);
    } else {
        fused_legacy<<<1024, 256, 0, stream>>>(query, b_off, b_attn, b_val, b_out,
                                               Wswz, Wout_swz, out);
    }
}